// Round 1
// baseline (20.120 us; speedup 1.0000x reference)
//
#include <hip/hip_runtime.h>

// SvmLoss: N=8192, RANK_RATIO=1.0 -> output == rank_loss (scalar f32).
// rank_loss = sum_{i,j} [time_i < time_j && status_i==1] * max(1 - lg_j + lg_i, 0)^2
//             / max(#pairs, 1),   lg = -logit
//
// Strategy: 2D tile the 8192x8192 pair space. 512 blocks = 32 i-chunks x 16
// j-chunks (JCHUNK=512). Stage j-chunk (lg, time) in LDS; inner-loop j address
// is wave-uniform -> LDS broadcast (conflict-free). Deterministic 2-pass
// reduction (no float atomics).

constexpr int N_      = 8192;
constexpr int BLK     = 256;
constexpr int JCHUNK  = 512;
constexpr int NBI     = N_ / BLK;     // 32 i-chunks
constexpr int NJC     = N_ / JCHUNK;  // 16 j-chunks
constexpr int GRID    = NBI * NJC;    // 512 blocks (2 per CU)

__global__ __launch_bounds__(BLK) void svm_partial(
        const float* __restrict__ logit,
        const float* __restrict__ st,      // [N][2]: status, time interleaved
        float* __restrict__ psum,
        int* __restrict__ pcnt) {
    __shared__ float lg_s[JCHUNK];
    __shared__ float tm_s[JCHUNK];

    const int bi = blockIdx.x % NBI;   // i-chunk
    const int bj = blockIdx.x / NBI;   // j-chunk
    const int j0 = bj * JCHUNK;

    // Stage j-chunk into LDS (coalesced; 4 KB total)
    for (int t = threadIdx.x; t < JCHUNK; t += BLK) {
        lg_s[t] = -logit[j0 + t];
        tm_s[t] = st[2 * (j0 + t) + 1];
    }
    __syncthreads();

    const int   i   = bi * BLK + (int)threadIdx.x;
    const float lgi = -logit[i];
    const float sti = st[2 * i];
    const float tmi = st[2 * i + 1];

    float sum = 0.0f;
    int   cnt = 0;
    if (sti == 1.0f) {                 // mask needs status[i]==1
        const float base = 1.0f + lgi; // hinge = base - lg[j]
        #pragma unroll 8
        for (int j = 0; j < JCHUNK; ++j) {
            float h  = fmaxf(base - lg_s[j], 0.0f);
            bool  m  = tmi < tm_s[j];
            float hm = m ? h : 0.0f;
            sum = fmaf(hm, hm, sum);
            cnt += (int)m;
        }
    }

    // Deterministic block reduction: wave64 shuffle tree, then LDS across waves
    for (int off = 32; off > 0; off >>= 1) {
        sum += __shfl_down(sum, off, 64);
        cnt += __shfl_down(cnt, off, 64);
    }
    __shared__ float wsum[BLK / 64];
    __shared__ int   wcnt[BLK / 64];
    const int lane = threadIdx.x & 63;
    const int wid  = threadIdx.x >> 6;
    if (lane == 0) { wsum[wid] = sum; wcnt[wid] = cnt; }
    __syncthreads();
    if (threadIdx.x == 0) {
        float s = 0.0f; int c = 0;
        for (int w = 0; w < BLK / 64; ++w) { s += wsum[w]; c += wcnt[w]; }
        psum[blockIdx.x] = s;
        pcnt[blockIdx.x] = c;
    }
}

__global__ __launch_bounds__(GRID) void svm_final(
        const float* __restrict__ psum,
        const int* __restrict__ pcnt,
        float* __restrict__ out) {
    float s = psum[threadIdx.x];
    int   c = pcnt[threadIdx.x];
    for (int off = 32; off > 0; off >>= 1) {
        s += __shfl_down(s, off, 64);
        c += __shfl_down(c, off, 64);
    }
    __shared__ float wsum[GRID / 64];
    __shared__ int   wcnt[GRID / 64];
    const int lane = threadIdx.x & 63;
    const int wid  = threadIdx.x >> 6;
    if (lane == 0) { wsum[wid] = s; wcnt[wid] = c; }
    __syncthreads();
    if (threadIdx.x == 0) {
        float S = 0.0f; int C = 0;
        for (int w = 0; w < GRID / 64; ++w) { S += wsum[w]; C += wcnt[w]; }
        out[0] = S / (float)max(C, 1);   // n_pairs = max(sum(mask),1)
    }
}

extern "C" void kernel_launch(void* const* d_in, const int* in_sizes, int n_in,
                              void* d_out, int out_size, void* d_ws, size_t ws_size,
                              hipStream_t stream) {
    const float* logit = (const float*)d_in[0];   // (N,1) f32
    const float* st    = (const float*)d_in[1];   // (N,2) f32 status,time
    float* psum = (float*)d_ws;
    int*   pcnt = (int*)((float*)d_ws + GRID);

    svm_partial<<<GRID, BLK, 0, stream>>>(logit, st, psum, pcnt);
    svm_final<<<1, GRID, 0, stream>>>(psum, pcnt, (float*)d_out);
}